// Round 1
// baseline (804.802 us; speedup 1.0000x reference)
//
#include <hip/hip_runtime.h>
#include <stdint.h>

#define H 512
#define BATCH 64
#define NIN 256
#define NOUT 128
#define TTOT 1000

// ---------------- phase 0: transpose W_rec -> WrecT[j][h] = W_rec[h][j] ----
__global__ __launch_bounds__(256) void k_transpose(const float* __restrict__ W,
                                                   float* __restrict__ WT) {
  __shared__ float tile[32][33];
  int j0 = blockIdx.x * 32;
  int h0 = blockIdx.y * 32;
  int tx = threadIdx.x, ty = threadIdx.y;  // 32 x 8
  for (int r = ty; r < 32; r += 8) tile[r][tx] = W[(h0 + r) * H + j0 + tx];
  __syncthreads();
  for (int r = ty; r < 32; r += 8) WT[(j0 + r) * H + h0 + tx] = tile[tx][r];
}

// ---------------- phase 1: xpT[b][h][t-t0] = sum_i x[t][b][i] * Win[h][i] ---
// f32 vector-FMA tiled GEMM, 64x64 tile, KB=64.
#define KB 64
#define LDSP 68
__global__ __launch_bounds__(256) void k_xproj(const float* __restrict__ x,
                                               const float* __restrict__ Win,
                                               float* __restrict__ xpT,
                                               int t0, int CH) {
  __shared__ float As[64][LDSP];  // h rows x k
  __shared__ float Bs[64][LDSP];  // t rows x k
  const int b = blockIdx.x;   // batch
  const int ht = blockIdx.y;  // h tile (8)
  const int tt = blockIdx.z;  // t tile within chunk
  const int tid = threadIdx.x;
  const int tmod = tid & 15;  // 0..15
  const int tdiv = tid >> 4;  // 0..15
  float acc[4][4] = {};
  for (int k0 = 0; k0 < NIN; k0 += KB) {
#pragma unroll
    for (int p = 0; p < 4; ++p) {
      int row = p * 16 + tdiv;
      int k4 = tmod * 4;
      float4 av = *reinterpret_cast<const float4*>(
          &Win[(size_t)(ht * 64 + row) * NIN + k0 + k4]);
      *reinterpret_cast<float4*>(&As[row][k4]) = av;
      int t = t0 + tt * 64 + row;
      float4 bv = make_float4(0.f, 0.f, 0.f, 0.f);
      if (t < TTOT)
        bv = *reinterpret_cast<const float4*>(
            &x[((size_t)t * BATCH + b) * NIN + k0 + k4]);
      *reinterpret_cast<float4*>(&Bs[row][k4]) = bv;
    }
    __syncthreads();
#pragma unroll
    for (int k4 = 0; k4 < KB; k4 += 4) {
      float4 a[4], bb[4];
#pragma unroll
      for (int i = 0; i < 4; ++i)
        a[i] = *reinterpret_cast<const float4*>(&As[tdiv * 4 + i][k4]);
#pragma unroll
      for (int j = 0; j < 4; ++j)
        bb[j] = *reinterpret_cast<const float4*>(&Bs[tmod * 4 + j][k4]);
#pragma unroll
      for (int i = 0; i < 4; ++i)
#pragma unroll
        for (int j = 0; j < 4; ++j)
          acc[i][j] += a[i].x * bb[j].x + a[i].y * bb[j].y +
                       a[i].z * bb[j].z + a[i].w * bb[j].w;
    }
    __syncthreads();
  }
  // store: h = ht*64 + tdiv*4+i ; tloc = tt*64 + tmod*4+j
  int tloc0 = tt * 64 + tmod * 4;
#pragma unroll
  for (int i = 0; i < 4; ++i) {
    int hh = ht * 64 + tdiv * 4 + i;
    float* dst = &xpT[((size_t)b * H + hh) * CH + tloc0];
    if (t0 + tloc0 + 3 < TTOT) {
      *reinterpret_cast<float4*>(dst) =
          make_float4(acc[i][0], acc[i][1], acc[i][2], acc[i][3]);
    } else {
#pragma unroll
      for (int j = 0; j < 4; ++j)
        if (t0 + tloc0 + j < TTOT) dst[j] = acc[i][j];
    }
  }
}

// ---------------- phase 2: sequential scan, 1 block per batch ---------------
__global__ __launch_bounds__(512) void k_scan(const float* __restrict__ xpT,
                                              const float* __restrict__ WrecT,
                                              float* __restrict__ state,
                                              int t0, int nsteps, int CH) {
  const int b = blockIdx.x;
  const int h = threadIdx.x;
  const int idx = b * H + h;
  const int wid = h >> 6;
  const int lane = h & 63;
  float* Sv = state;
  float* Sa0 = state + 32768;
  float* Sa1 = state + 2 * 32768;
  float* Sp = state + 3 * 32768;
  float* Sr = state + 4 * 32768;

  float v, a0, a1, psc, rsum;
  if (t0 == 0) {
    v = -60.f; a0 = 0.f; a1 = 0.f; psc = 0.f; rsum = 0.f;
  } else {
    v = Sv[idx]; a0 = Sa0[idx]; a1 = Sa1[idx]; psc = Sp[idx]; rsum = Sr[idx];
  }
  const float4* row4 = reinterpret_cast<const float4*>(xpT + (size_t)idx * CH);
  __shared__ unsigned int wany[8];
  __shared__ unsigned long long wbal[8];
  const float D0 = 0.90483741803595957316f;  // exp(-0.1)
  const float D1 = 0.81873075307798185867f;  // exp(-0.2)
  const float DS = 0.81873075307798185867f;  // exp(-1/5)

  float4 Ia = row4[0], Ib = row4[1];
  for (int w = 0; w < nsteps; w += 8) {
    float4 nIa = make_float4(0.f, 0.f, 0.f, 0.f);
    float4 nIb = nIa;
    if (w + 8 < nsteps) {
      nIa = row4[(w >> 2) + 2];
      nIb = row4[(w >> 2) + 3];
    }
    float Iv[8] = {Ia.x, Ia.y, Ia.z, Ia.w, Ib.x, Ib.y, Ib.z, Ib.w};
    // speculative fast path: assume no spikes in this window
    float sv = v, s0 = a0, s1 = a1, sp = psc, sr = rsum;
    unsigned int spk = 0;
#pragma unroll
    for (int s = 0; s < 8; ++s) {
      float It = Iv[s] + psc + a0 + a1;
      float vint = 0.95f * v + 0.5f * It - 3.0f;
      bool fire = vint >= -45.f;
      spk |= fire ? (1u << s) : 0u;
      v = fire ? -60.f : vint;
      a0 = a0 * D0 + (fire ? 1.f : 0.f);
      a1 = a1 * D1 + (fire ? -2.f : 0.f);
      psc *= DS;
      rsum += fire ? 1.f : 0.f;
    }
    unsigned long long bal = __ballot(spk != 0u);
    if (lane == 0) wany[wid] = (bal != 0ull) ? 1u : 0u;
    __syncthreads();
    unsigned int any = wany[0] | wany[1] | wany[2] | wany[3] | wany[4] |
                       wany[5] | wany[6] | wany[7];
    if (any) {
      // rollback + exact replay with recurrent input (rare path)
      v = sv; a0 = s0; a1 = s1; psc = sp; rsum = sr;
      for (int s = 0; s < 8; ++s) {
        float It = Iv[s] + psc + a0 + a1;
        float vint = 0.95f * v + 0.5f * It - 3.0f;
        bool fire = vint >= -45.f;
        unsigned long long bb = __ballot(fire);
        __syncthreads();  // previous wbal reads complete
        if (lane == 0) wbal[wid] = bb;
        __syncthreads();
        float rec = 0.f;
        for (int g = 0; g < 8; ++g) {
          unsigned long long m = wbal[g];
          while (m) {
            int j = (g << 6) + __builtin_ctzll(m);
            m &= m - 1;
            rec += WrecT[(size_t)j * H + h];
          }
        }
        v = fire ? -60.f : vint;
        a0 = a0 * D0 + (fire ? 1.f : 0.f);
        a1 = a1 * D1 + (fire ? -2.f : 0.f);
        psc = psc * DS + rec;
        rsum += fire ? 1.f : 0.f;
      }
    }
    __syncthreads();  // protect wany before next window overwrite
    Ia = nIa;
    Ib = nIb;
  }
  Sv[idx] = v; Sa0[idx] = a0; Sa1[idx] = a1; Sp[idx] = psc; Sr[idx] = rsum;
}

// ---------------- phase 3: out[b][o] = (rsum[b][:]/T) . Wout[o][:] ----------
__global__ __launch_bounds__(128) void k_out(const float* __restrict__ rsum,
                                             const float* __restrict__ Wout,
                                             float* __restrict__ out) {
  int b = blockIdx.x;
  int o = threadIdx.x;
  __shared__ float r[H];
  for (int i = threadIdx.x; i < H; i += 128)
    r[i] = rsum[b * H + i] * (1.0f / TTOT);
  __syncthreads();
  const float4* wrow = reinterpret_cast<const float4*>(&Wout[(size_t)o * H]);
  float acc = 0.f;
#pragma unroll 4
  for (int q = 0; q < H / 4; ++q) {
    float4 wv = wrow[q];
    acc += wv.x * r[q * 4 + 0] + wv.y * r[q * 4 + 1] + wv.z * r[q * 4 + 2] +
           wv.w * r[q * 4 + 3];
  }
  out[b * NOUT + o] = acc;
}

extern "C" void kernel_launch(void* const* d_in, const int* in_sizes, int n_in,
                              void* d_out, int out_size, void* d_ws,
                              size_t ws_size, hipStream_t stream) {
  const float* x = (const float*)d_in[0];     // (1000,64,256)
  const float* Win = (const float*)d_in[1];   // (512,256)
  const float* Wrec = (const float*)d_in[2];  // (512,512)
  const float* Wout = (const float*)d_in[3];  // (128,512)
  float* out = (float*)d_out;                 // (64,128)

  char* ws = (char*)d_ws;
  float* state = (float*)ws;                        // 5 * 32768 f32 = 640 KB
  float* WrecT = (float*)(ws + 5 * 32768 * 4);      // 1 MB, offset 640 KB
  float* xpT = (float*)(ws + 2 * 1024 * 1024);      // chunk buffer

  // pick chunk length CH (multiple of 64, padded T) to fit workspace
  size_t avail = (ws_size > 2 * 1024 * 1024) ? ws_size - 2 * 1024 * 1024 : 0;
  int CH = (int)(avail / ((size_t)BATCH * H * 4));  // steps that fit
  CH = (CH / 64) * 64;
  if (CH > 1024) CH = 1024;
  if (CH < 64) CH = 64;  // assume ws_size is at least ~10.4 MB

  hipLaunchKernelGGL(k_transpose, dim3(16, 16), dim3(32, 8), 0, stream, Wrec,
                     WrecT);
  for (int t0 = 0; t0 < TTOT; t0 += CH) {
    int nst = TTOT - t0;
    if (nst > CH) nst = CH;           // always a multiple of 8
    int ntt = (nst + 63) / 64;
    hipLaunchKernelGGL(k_xproj, dim3(BATCH, 8, ntt), dim3(256), 0, stream, x,
                       Win, xpT, t0, CH);
    hipLaunchKernelGGL(k_scan, dim3(BATCH), dim3(512), 0, stream, xpT, WrecT,
                       state, t0, nst, CH);
  }
  hipLaunchKernelGGL(k_out, dim3(BATCH), dim3(128), 0, stream, state + 4 * 32768,
                     Wout, out);
}

// Round 2
// 163.565 us; speedup vs baseline: 4.9204x; 4.9204x over previous
//
#include <hip/hip_runtime.h>
#include <stdint.h>

#define H 512
#define BATCH 64
#define NIN 256
#define NOUT 128
#define TTOT 1000
#define MTOT (TTOT * BATCH)  // 64000 rows of the projection GEMM

typedef __attribute__((ext_vector_type(8))) short s16x8;
typedef __attribute__((ext_vector_type(4))) float f32x4;
typedef __attribute__((ext_vector_type(8))) unsigned short u16x8;

static __device__ __forceinline__ unsigned short f2bf(float f) {
  union { float f; uint32_t u; } x; x.f = f;
  uint32_t r = x.u + 0x7FFFu + ((x.u >> 16) & 1u);
  return (unsigned short)(r >> 16);
}
static __device__ __forceinline__ float bf2f(unsigned short b) {
  union { uint32_t u; float f; } x; x.u = ((uint32_t)b) << 16;
  return x.f;
}
__device__ __forceinline__ void gload_lds16(const void* g, void* l) {
  __builtin_amdgcn_global_load_lds(
      (const __attribute__((address_space(1))) uint32_t*)g,
      (__attribute__((address_space(3))) uint32_t*)l, 16, 0, 0);
}

// ---------------- cast f32 -> bf16, 8 elems/thread, grid-stride ------------
__global__ __launch_bounds__(256) void k_cast(const float* __restrict__ in,
                                              unsigned short* __restrict__ out,
                                              int n8) {
  for (int g = blockIdx.x * blockDim.x + threadIdx.x; g < n8;
       g += gridDim.x * blockDim.x) {
    const float4* p = (const float4*)in + (size_t)g * 2;
    float4 a = p[0], b = p[1];
    u16x8 o;
    o[0] = f2bf(a.x); o[1] = f2bf(a.y); o[2] = f2bf(a.z); o[3] = f2bf(a.w);
    o[4] = f2bf(b.x); o[5] = f2bf(b.y); o[6] = f2bf(b.z); o[7] = f2bf(b.w);
    *(u16x8*)(out + (size_t)g * 8) = o;
  }
}

// ---------------- transpose W_rec -> WrecT[j][h] = W_rec[h][j] (f32) --------
__global__ __launch_bounds__(256) void k_transpose(const float* __restrict__ W,
                                                   float* __restrict__ WT) {
  __shared__ float tile[32][33];
  int j0 = blockIdx.x * 32;
  int h0 = blockIdx.y * 32;
  int tx = threadIdx.x, ty = threadIdx.y;  // 32 x 8
  for (int r = ty; r < 32; r += 8) tile[r][tx] = W[(h0 + r) * H + j0 + tx];
  __syncthreads();
  for (int r = ty; r < 32; r += 8) WT[(j0 + r) * H + h0 + tx] = tile[tx][r];
}

// ---------------- bf16 MFMA GEMM: C(64000x512) = A(64000x256) . B^T ---------
// A = x flattened (t*B+b, i) bf16 ; B^T = Win (512x256) bf16 ; C = xp bf16.
// 128x128 tile, BK=64, 4 waves (2x2 of 64x64), 16x16x32 MFMA.
// global_load_lds width=16 with pre-swizzled source (T2 st-style XOR), so
// ds_read_b128 frag loads are 2-way max (free).
__global__ __launch_bounds__(256) void k_xproj_mfma(
    const unsigned short* __restrict__ A, const unsigned short* __restrict__ B,
    unsigned short* __restrict__ C) {
  __shared__ __align__(16) char lds[32768];
  char* ldsA = lds;
  char* ldsB = lds + 16384;
  const int bid = blockIdx.x;
  // XCD-aware swizzle: 2000 % 8 == 0 -> bijective chunked mapping
  const int wg = (bid & 7) * 250 + (bid >> 3);
  const int bn = wg & 3;    // 4 N-tiles (512/128)
  const int bm = wg >> 2;   // 500 M-tiles
  const int tid = threadIdx.x;
  const int wave = tid >> 6;
  const int l = tid & 63;
  const int wr = wave >> 1, wc = wave & 1;
  const int lrow = l >> 3;                       // 0..7 (row within 8-row chunk)
  const int lcolb = (((l & 7) ^ lrow) << 4);     // swizzled byte col in [0,128)
  const int fr = l & 15;
  const int fq = l >> 4;

  f32x4 acc[4][4] = {};

  const char* Ab = (const char*)(A + (size_t)bm * 128 * 256);
  const char* Bb = (const char*)(B + (size_t)bn * 128 * 256);

  for (int ks = 0; ks < 4; ++ks) {
    const int kb = ks * 128;  // k0 byte offset within a 512-B row
#pragma unroll
    for (int i = 0; i < 4; ++i) {
      const int q = wave * 4 + i;       // 8-row chunk index, 16 chunks total
      const int row = q * 8 + lrow;
      gload_lds16(Ab + (size_t)row * 512 + kb + lcolb, ldsA + q * 1024);
      gload_lds16(Bb + (size_t)row * 512 + kb + lcolb, ldsB + q * 1024);
    }
    __syncthreads();
#pragma unroll
    for (int kk = 0; kk < 2; ++kk) {
      const int cbyte = kk * 64 + fq * 16;
      s16x8 a[4], b[4];
#pragma unroll
      for (int m = 0; m < 4; ++m) {
        const int row = wr * 64 + m * 16 + fr;
        a[m] = *(const s16x8*)(ldsA + row * 128 + (cbyte ^ ((row & 7) << 4)));
      }
#pragma unroll
      for (int n = 0; n < 4; ++n) {
        const int row = wc * 64 + n * 16 + fr;
        b[n] = *(const s16x8*)(ldsB + row * 128 + (cbyte ^ ((row & 7) << 4)));
      }
#pragma unroll
      for (int m = 0; m < 4; ++m)
#pragma unroll
        for (int n = 0; n < 4; ++n)
          acc[m][n] = __builtin_amdgcn_mfma_f32_16x16x32_bf16(a[m], b[n],
                                                              acc[m][n], 0, 0, 0);
    }
    __syncthreads();
  }
  // epilogue: repack 128x128 bf16 tile in LDS, then coalesced 16B stores
  unsigned short* ldsC = (unsigned short*)lds;
#pragma unroll
  for (int m = 0; m < 4; ++m) {
    const int r0 = wr * 64 + m * 16 + fq * 4;
#pragma unroll
    for (int n = 0; n < 4; ++n) {
      const int col = wc * 64 + n * 16 + fr;
      f32x4 c = acc[m][n];
#pragma unroll
      for (int j = 0; j < 4; ++j) ldsC[(r0 + j) * 128 + col] = f2bf(c[j]);
    }
  }
  __syncthreads();
  const size_t cbase = ((size_t)bm * 128) * 512 + (size_t)bn * 128;
#pragma unroll
  for (int i = 0; i < 8; ++i) {
    const int r = i * 16 + (tid >> 4);
    const int cb2 = (tid & 15) * 16;
    float4 v = *(const float4*)(lds + r * 256 + cb2);
    *(float4*)((char*)(C + cbase + (size_t)r * 512) + cb2) = v;
  }
}

// ---------------- sequential scan + fused output GEMV -----------------------
// 1 block per batch, 512 threads (1 per neuron), full T=1000 in one launch.
// Speculative 8-step windows; exact ballot-replay if any spike fired.
__global__ __launch_bounds__(512) void k_scan(
    const unsigned short* __restrict__ xp,  // (1000*64, 512) bf16
    const float* __restrict__ WrecT,        // (512,512): WrecT[j][h]=Wrec[h][j]
    const float* __restrict__ Wout,         // (128,512)
    float* __restrict__ out) {              // (64,128)
  const int b = blockIdx.x;
  const int h = threadIdx.x;
  const int wid = h >> 6;
  const int lane = h & 63;
  __shared__ unsigned int wany[8];
  __shared__ unsigned long long wbal[8];
  __shared__ float rbuf[512];
  __shared__ float pbuf[4][128];

  const unsigned short* xrow = xp + b * H + h;  // stride per t: BATCH*H = 32768
  const float D0 = 0.90483741803595957316f;  // exp(-0.1)
  const float D1 = 0.81873075307798185867f;  // exp(-0.2)
  const float DS = 0.81873075307798185867f;  // exp(-1/5)

  float v = -60.f, a0 = 0.f, a1 = 0.f, psc = 0.f, rsum = 0.f;
  unsigned short pf[8];
#pragma unroll
  for (int s = 0; s < 8; ++s) pf[s] = xrow[(size_t)s * 32768];

  for (int w = 0; w < TTOT; w += 8) {
    float Iv[8];
#pragma unroll
    for (int s = 0; s < 8; ++s) Iv[s] = bf2f(pf[s]);
    // prefetch next window (issues early; consumed next iteration)
#pragma unroll
    for (int s = 0; s < 8; ++s) {
      int t = w + 8 + s;
      pf[s] = (t < TTOT) ? xrow[(size_t)t * 32768] : (unsigned short)0;
    }
    // speculative fast path: assume no spikes in this window
    float sv = v, s0 = a0, s1 = a1, sp = psc, sr = rsum;
    unsigned int spk = 0;
#pragma unroll
    for (int s = 0; s < 8; ++s) {
      float It = Iv[s] + psc + a0 + a1;
      float vint = 0.95f * v + 0.5f * It - 3.0f;
      bool fire = vint >= -45.f;
      spk |= fire ? (1u << s) : 0u;
      v = fire ? -60.f : vint;
      a0 = a0 * D0 + (fire ? 1.f : 0.f);
      a1 = a1 * D1 + (fire ? -2.f : 0.f);
      psc *= DS;
      rsum += fire ? 1.f : 0.f;
    }
    unsigned long long bal = __ballot(spk != 0u);
    if (lane == 0) wany[wid] = (bal != 0ull) ? 1u : 0u;
    __syncthreads();
    unsigned int any = wany[0] | wany[1] | wany[2] | wany[3] | wany[4] |
                       wany[5] | wany[6] | wany[7];
    if (any) {
      // rollback + exact replay with recurrent input (rare path)
      v = sv; a0 = s0; a1 = s1; psc = sp; rsum = sr;
      for (int s = 0; s < 8; ++s) {
        float It = Iv[s] + psc + a0 + a1;
        float vint = 0.95f * v + 0.5f * It - 3.0f;
        bool fire = vint >= -45.f;
        unsigned long long bb = __ballot(fire);
        __syncthreads();  // previous wbal reads complete
        if (lane == 0) wbal[wid] = bb;
        __syncthreads();
        float rec = 0.f;
        for (int g = 0; g < 8; ++g) {
          unsigned long long m = wbal[g];
          while (m) {
            int j = (g << 6) + __builtin_ctzll(m);
            m &= m - 1;
            rec += WrecT[(size_t)j * H + h];
          }
        }
        v = fire ? -60.f : vint;
        a0 = a0 * D0 + (fire ? 1.f : 0.f);
        a1 = a1 * D1 + (fire ? -2.f : 0.f);
        psc = psc * DS + rec;
        rsum += fire ? 1.f : 0.f;
      }
    }
    __syncthreads();  // protect wany before next window overwrite
  }

  // fused output: out[b][o] = (rsum/T) . Wout[o][:]
  rbuf[h] = rsum * 0.001f;
  __syncthreads();
  const int o = h & 127, part = h >> 7;
  const float4* wrow = (const float4*)(Wout + (size_t)o * H + part * 128);
  const float* rb = rbuf + part * 128;
  float acc = 0.f;
#pragma unroll 8
  for (int q = 0; q < 32; ++q) {
    float4 wv = wrow[q];
    acc += wv.x * rb[q * 4] + wv.y * rb[q * 4 + 1] + wv.z * rb[q * 4 + 2] +
           wv.w * rb[q * 4 + 3];
  }
  pbuf[part][o] = acc;
  __syncthreads();
  if (h < NOUT)
    out[b * NOUT + h] = pbuf[0][h] + pbuf[1][h] + pbuf[2][h] + pbuf[3][h];
}

extern "C" void kernel_launch(void* const* d_in, const int* in_sizes, int n_in,
                              void* d_out, int out_size, void* d_ws,
                              size_t ws_size, hipStream_t stream) {
  const float* x = (const float*)d_in[0];     // (1000,64,256)
  const float* Win = (const float*)d_in[1];   // (512,256)
  const float* Wrec = (const float*)d_in[2];  // (512,512)
  const float* Wout = (const float*)d_in[3];  // (128,512)
  float* out = (float*)d_out;                 // (64,128)

  char* ws = (char*)d_ws;
  float* WrecT = (float*)ws;                                   // 1 MB
  unsigned short* Winb = (unsigned short*)(ws + (1 << 20));    // 256 KB
  unsigned short* xb = (unsigned short*)(ws + (2 << 20));      // 32 MB
  unsigned short* xpb = (unsigned short*)(ws + ((size_t)34 << 20));  // 64 MB
  // total ws use: 98 MB (round-0 run proved ws_size >= ~130 MB)

  hipLaunchKernelGGL(k_cast, dim3(2048), dim3(256), 0, stream, x, xb,
                     MTOT * NIN / 8);
  hipLaunchKernelGGL(k_cast, dim3(64), dim3(256), 0, stream, Win, Winb,
                     H * NIN / 8);
  hipLaunchKernelGGL(k_transpose, dim3(16, 16), dim3(32, 8), 0, stream, Wrec,
                     WrecT);
  hipLaunchKernelGGL(k_xproj_mfma, dim3(2000), dim3(256), 0, stream, xb, Winb,
                     xpb);
  hipLaunchKernelGGL(k_scan, dim3(BATCH), dim3(512), 0, stream, xpb, WrecT,
                     Wout, out);
}

// Round 3
// 88.127 us; speedup vs baseline: 9.1323x; 1.8560x over previous
//
#include <hip/hip_runtime.h>
#include <stdint.h>

#define H 512
#define BATCH 64
#define NIN 256
#define NOUT 128
#define TTOT 1000
#define MTOT (TTOT * BATCH)  // 64000 rows of the projection GEMM
#define CHL 20               // chunk length for time-parallel scan
#define NCH 50               // number of chunks (CHL*NCH == TTOT)

typedef __attribute__((ext_vector_type(8))) short s16x8;
typedef __attribute__((ext_vector_type(4))) float f32x4;
typedef __attribute__((ext_vector_type(8))) unsigned short u16x8;

static __device__ __forceinline__ unsigned short f2bf(float f) {
  union { float f; uint32_t u; } x; x.f = f;
  uint32_t r = x.u + 0x7FFFu + ((x.u >> 16) & 1u);
  return (unsigned short)(r >> 16);
}
static __device__ __forceinline__ float bf2f(unsigned short b) {
  union { uint32_t u; float f; } x; x.u = ((uint32_t)b) << 16;
  return x.f;
}
__device__ __forceinline__ void gload_lds16(const void* g, void* l) {
  __builtin_amdgcn_global_load_lds(
      (const __attribute__((address_space(1))) uint32_t*)g,
      (__attribute__((address_space(3))) uint32_t*)l, 16, 0, 0);
}

// ---------------- cast f32 -> bf16, 8 elems/thread, grid-stride ------------
__global__ __launch_bounds__(256) void k_cast(const float* __restrict__ in,
                                              unsigned short* __restrict__ out,
                                              int n8) {
  for (int g = blockIdx.x * blockDim.x + threadIdx.x; g < n8;
       g += gridDim.x * blockDim.x) {
    const float4* p = (const float4*)in + (size_t)g * 2;
    float4 a = p[0], b = p[1];
    u16x8 o;
    o[0] = f2bf(a.x); o[1] = f2bf(a.y); o[2] = f2bf(a.z); o[3] = f2bf(a.w);
    o[4] = f2bf(b.x); o[5] = f2bf(b.y); o[6] = f2bf(b.z); o[7] = f2bf(b.w);
    *(u16x8*)(out + (size_t)g * 8) = o;
  }
}

// ---------------- transpose W_rec -> WrecT[j][h] = W_rec[h][j] (f32) --------
__global__ __launch_bounds__(256) void k_transpose(const float* __restrict__ W,
                                                   float* __restrict__ WT) {
  __shared__ float tile[32][33];
  int j0 = blockIdx.x * 32;
  int h0 = blockIdx.y * 32;
  int tx = threadIdx.x, ty = threadIdx.y;  // 32 x 8
  for (int r = ty; r < 32; r += 8) tile[r][tx] = W[(h0 + r) * H + j0 + tx];
  __syncthreads();
  for (int r = ty; r < 32; r += 8) WT[(j0 + r) * H + h0 + tx] = tile[tx][r];
}

// ---------------- bf16 MFMA GEMM: C(64000x512) = A(64000x256) . B^T ---------
// A = x flattened (t*B+b, i) bf16 ; B^T = Win (512x256) bf16 ; C = xp bf16.
// 128x128 tile, BK=64, 4 waves (2x2 of 64x64), 16x16x32 MFMA.
__global__ __launch_bounds__(256) void k_xproj_mfma(
    const unsigned short* __restrict__ A, const unsigned short* __restrict__ B,
    unsigned short* __restrict__ C) {
  __shared__ __align__(16) char lds[32768];
  char* ldsA = lds;
  char* ldsB = lds + 16384;
  const int bid = blockIdx.x;
  // XCD-aware swizzle: 2000 % 8 == 0 -> bijective chunked mapping
  const int wg = (bid & 7) * 250 + (bid >> 3);
  const int bn = wg & 3;    // 4 N-tiles (512/128)
  const int bm = wg >> 2;   // 500 M-tiles
  const int tid = threadIdx.x;
  const int wave = tid >> 6;
  const int l = tid & 63;
  const int wr = wave >> 1, wc = wave & 1;
  const int lrow = l >> 3;                       // 0..7 (row within 8-row chunk)
  const int lcolb = (((l & 7) ^ lrow) << 4);     // swizzled byte col in [0,128)
  const int fr = l & 15;
  const int fq = l >> 4;

  f32x4 acc[4][4] = {};

  const char* Ab = (const char*)(A + (size_t)bm * 128 * 256);
  const char* Bb = (const char*)(B + (size_t)bn * 128 * 256);

  for (int ks = 0; ks < 4; ++ks) {
    const int kb = ks * 128;  // k0 byte offset within a 512-B row
#pragma unroll
    for (int i = 0; i < 4; ++i) {
      const int q = wave * 4 + i;       // 8-row chunk index, 16 chunks total
      const int row = q * 8 + lrow;
      gload_lds16(Ab + (size_t)row * 512 + kb + lcolb, ldsA + q * 1024);
      gload_lds16(Bb + (size_t)row * 512 + kb + lcolb, ldsB + q * 1024);
    }
    __syncthreads();
#pragma unroll
    for (int kk = 0; kk < 2; ++kk) {
      const int cbyte = kk * 64 + fq * 16;
      s16x8 a[4], b[4];
#pragma unroll
      for (int m = 0; m < 4; ++m) {
        const int row = wr * 64 + m * 16 + fr;
        a[m] = *(const s16x8*)(ldsA + row * 128 + (cbyte ^ ((row & 7) << 4)));
      }
#pragma unroll
      for (int n = 0; n < 4; ++n) {
        const int row = wc * 64 + n * 16 + fr;
        b[n] = *(const s16x8*)(ldsB + row * 128 + (cbyte ^ ((row & 7) << 4)));
      }
#pragma unroll
      for (int m = 0; m < 4; ++m)
#pragma unroll
        for (int n = 0; n < 4; ++n)
          acc[m][n] = __builtin_amdgcn_mfma_f32_16x16x32_bf16(a[m], b[n],
                                                              acc[m][n], 0, 0, 0);
    }
    __syncthreads();
  }
  // epilogue: repack 128x128 bf16 tile in LDS, then coalesced 16B stores
  unsigned short* ldsC = (unsigned short*)lds;
#pragma unroll
  for (int m = 0; m < 4; ++m) {
    const int r0 = wr * 64 + m * 16 + fq * 4;
#pragma unroll
    for (int n = 0; n < 4; ++n) {
      const int col = wc * 64 + n * 16 + fr;
      f32x4 c = acc[m][n];
#pragma unroll
      for (int j = 0; j < 4; ++j) ldsC[(r0 + j) * 128 + col] = f2bf(c[j]);
    }
  }
  __syncthreads();
  const size_t cbase = ((size_t)bm * 128) * 512 + (size_t)bn * 128;
#pragma unroll
  for (int i = 0; i < 8; ++i) {
    const int r = i * 16 + (tid >> 4);
    const int cb2 = (tid & 15) * 16;
    float4 v = *(const float4*)(lds + r * 256 + cb2);
    *(float4*)((char*)(C + cbase + (size_t)r * 512) + cb2) = v;
  }
}

// ---------------- time-parallel linear scan (exact while no spikes) ---------
// Until the first spike, psc==0 and iasc==0, so v follows the scalar affine
// recurrence v' = 0.95 v + (0.5*I - 3) independently per (b,h). We compute it
// chunk-parallel, then *verify* no membrane ever comes within 0.5 mV of
// threshold; any batch that does falls back to the exact sequential scan.

// A: per-chunk affine offset Bc[c][b][h] = sum_s 0.95^(CHL-1-s) * u(c*CHL+s)
__global__ __launch_bounds__(256) void k_affine(
    const unsigned short* __restrict__ xp, float* __restrict__ Bc) {
  const int g = blockIdx.x * 256 + threadIdx.x;  // 64hg * 64b * 50c = 204800
  const int hg = g & 63, b = (g >> 6) & 63, c = g >> 12;
  const unsigned short* p = xp + ((size_t)(c * CHL) * 64 + b) * 512 + hg * 8;
  float acc[8] = {};
#pragma unroll
  for (int s = 0; s < CHL; ++s) {
    u16x8 xv = *(const u16x8*)(p + (size_t)s * 32768);
#pragma unroll
    for (int j = 0; j < 8; ++j)
      acc[j] = 0.95f * acc[j] + (0.5f * bf2f((unsigned short)xv[j]) - 3.0f);
  }
  float* dst = Bc + ((size_t)c * 64 + b) * 512 + hg * 8;
  *(float4*)dst = make_float4(acc[0], acc[1], acc[2], acc[3]);
  *(float4*)(dst + 4) = make_float4(acc[4], acc[5], acc[6], acc[7]);
}

// B: compose chunk-start voltages Vst[c][b][h]; also zero the batch flags.
__global__ __launch_bounds__(256) void k_compose(const float* __restrict__ Bc,
                                                 float* __restrict__ Vst,
                                                 int* __restrict__ flags) {
  if (blockIdx.x == 0 && threadIdx.x < BATCH) flags[threadIdx.x] = 0;
  const int g = blockIdx.x * 256 + threadIdx.x;  // 64hg * 64b = 4096
  const int hg = g & 63, b = g >> 6;
  const float AL = 0.35848592240854f;  // 0.95^20
  float v[8];
#pragma unroll
  for (int j = 0; j < 8; ++j) v[j] = -60.f;
  for (int c = 0; c < NCH; ++c) {
    size_t off = ((size_t)c * 64 + b) * 512 + hg * 8;
    float4 b0 = *(const float4*)(Bc + off);
    float4 b1 = *(const float4*)(Bc + off + 4);
    *(float4*)(Vst + off) = make_float4(v[0], v[1], v[2], v[3]);
    *(float4*)(Vst + off + 4) = make_float4(v[4], v[5], v[6], v[7]);
    v[0] = AL * v[0] + b0.x; v[1] = AL * v[1] + b0.y;
    v[2] = AL * v[2] + b0.z; v[3] = AL * v[3] + b0.w;
    v[4] = AL * v[4] + b1.x; v[5] = AL * v[5] + b1.y;
    v[6] = AL * v[6] + b1.z; v[7] = AL * v[7] + b1.w;
  }
}

// C: recompute each chunk trajectory from its exact start, screen threshold.
__global__ __launch_bounds__(256) void k_check(
    const unsigned short* __restrict__ xp, const float* __restrict__ Vst,
    int* __restrict__ flags) {
  const int g = blockIdx.x * 256 + threadIdx.x;
  const int hg = g & 63, b = (g >> 6) & 63, c = g >> 12;
  const size_t voff = ((size_t)c * 64 + b) * 512 + hg * 8;
  float4 v0 = *(const float4*)(Vst + voff);
  float4 v1 = *(const float4*)(Vst + voff + 4);
  float v[8] = {v0.x, v0.y, v0.z, v0.w, v1.x, v1.y, v1.z, v1.w};
  const unsigned short* p = xp + ((size_t)(c * CHL) * 64 + b) * 512 + hg * 8;
  bool cross = false;
#pragma unroll
  for (int s = 0; s < CHL; ++s) {
    u16x8 xv = *(const u16x8*)(p + (size_t)s * 32768);
#pragma unroll
    for (int j = 0; j < 8; ++j) {
      v[j] = 0.95f * v[j] + (0.5f * bf2f((unsigned short)xv[j]) - 3.0f);
      cross |= (v[j] >= -45.5f);  // 0.5 mV sound screening margin
    }
  }
  if (__any(cross) && (threadIdx.x & 63) == 0) flags[b] = 1;
}

// D: per batch — flagged: exact sequential GLIF scan; else zero output rows.
__global__ __launch_bounds__(512) void k_fallback(
    const unsigned short* __restrict__ xp, const float* __restrict__ WrecT,
    const float* __restrict__ Wout, const int* __restrict__ flags,
    float* __restrict__ out) {
  const int b = blockIdx.x;
  const int h = threadIdx.x;
  if (!flags[b]) {
    if (h < NOUT) out[b * NOUT + h] = 0.f;
    return;
  }
  const int wid = h >> 6;
  const int lane = h & 63;
  __shared__ unsigned long long wbal[8];
  __shared__ float rbuf[H];
  __shared__ float pbuf[4][NOUT];
  const float D0 = 0.90483741803595957316f;  // exp(-0.1)
  const float D1 = 0.81873075307798185867f;  // exp(-0.2)
  const float DS = 0.81873075307798185867f;  // exp(-1/5)
  float v = -60.f, a0 = 0.f, a1 = 0.f, psc = 0.f, rsum = 0.f;
  for (int t = 0; t < TTOT; ++t) {
    float I = bf2f(xp[((size_t)t * 64 + b) * 512 + h]);
    float It = I + psc + a0 + a1;
    float vint = 0.95f * v + 0.5f * It - 3.0f;
    bool fire = vint >= -45.f;
    unsigned long long bal = __ballot(fire);
    if (lane == 0) wbal[wid] = bal;
    __syncthreads();
    float rec = 0.f;
    for (int g = 0; g < 8; ++g) {
      unsigned long long m = wbal[g];
      while (m) {
        int j = (g << 6) + __builtin_ctzll(m);
        m &= m - 1;
        rec += WrecT[(size_t)j * H + h];
      }
    }
    v = fire ? -60.f : vint;
    a0 = a0 * D0 + (fire ? 1.f : 0.f);
    a1 = a1 * D1 + (fire ? -2.f : 0.f);
    psc = psc * DS + rec;
    rsum += fire ? 1.f : 0.f;
    __syncthreads();
  }
  // fused output GEMV: out[b][o] = (rsum/T) . Wout[o][:]
  rbuf[h] = rsum * 0.001f;
  __syncthreads();
  const int o = h & 127, part = h >> 7;
  const float4* wrow = (const float4*)(Wout + (size_t)o * H + part * 128);
  const float* rb = rbuf + part * 128;
  float acc = 0.f;
#pragma unroll 8
  for (int q = 0; q < 32; ++q) {
    float4 wv = wrow[q];
    acc += wv.x * rb[q * 4] + wv.y * rb[q * 4 + 1] + wv.z * rb[q * 4 + 2] +
           wv.w * rb[q * 4 + 3];
  }
  pbuf[part][o] = acc;
  __syncthreads();
  if (h < NOUT)
    out[b * NOUT + h] = pbuf[0][h] + pbuf[1][h] + pbuf[2][h] + pbuf[3][h];
}

extern "C" void kernel_launch(void* const* d_in, const int* in_sizes, int n_in,
                              void* d_out, int out_size, void* d_ws,
                              size_t ws_size, hipStream_t stream) {
  const float* x = (const float*)d_in[0];     // (1000,64,256)
  const float* Win = (const float*)d_in[1];   // (512,256)
  const float* Wrec = (const float*)d_in[2];  // (512,512)
  const float* Wout = (const float*)d_in[3];  // (128,512)
  float* out = (float*)d_out;                 // (64,128)

  char* ws = (char*)d_ws;
  float* WrecT = (float*)ws;                                 // 1 MB @ 0
  unsigned short* Winb = (unsigned short*)(ws + (1 << 20));  // 256 KB @ 1M
  unsigned short* xb = (unsigned short*)(ws + (2 << 20));    // 32 MB @ 2M
  unsigned short* xpb = (unsigned short*)(ws + ((size_t)34 << 20));  // 62.5 MB
  // xb region is dead after the GEMM -> reuse it for the scan scratch:
  int* flags = (int*)(ws + (2 << 20));                       // 256 B
  float* Bc = (float*)(ws + (2 << 20) + 4096);               // 6.55 MB
  float* Vst = (float*)(ws + (2 << 20) + 4096 + 6553600);    // 6.55 MB
  // peak footprint ~96.5 MB (same as round 1, proven to fit)

  hipLaunchKernelGGL(k_cast, dim3(2048), dim3(256), 0, stream, x, xb,
                     MTOT * NIN / 8);
  hipLaunchKernelGGL(k_cast, dim3(64), dim3(256), 0, stream, Win, Winb,
                     H * NIN / 8);
  hipLaunchKernelGGL(k_transpose, dim3(16, 16), dim3(32, 8), 0, stream, Wrec,
                     WrecT);
  hipLaunchKernelGGL(k_xproj_mfma, dim3(2000), dim3(256), 0, stream, xb, Winb,
                     xpb);
  hipLaunchKernelGGL(k_affine, dim3(800), dim3(256), 0, stream, xpb, Bc);
  hipLaunchKernelGGL(k_compose, dim3(16), dim3(256), 0, stream, Bc, Vst, flags);
  hipLaunchKernelGGL(k_check, dim3(800), dim3(256), 0, stream, xpb, Vst, flags);
  hipLaunchKernelGGL(k_fallback, dim3(BATCH), dim3(512), 0, stream, xpb, WrecT,
                     Wout, flags, out);
}